// Round 3
// baseline (2421.559 us; speedup 1.0000x reference)
//
#include <hip/hip_runtime.h>
#include <hip/hip_bf16.h>

#define NB 4
#define NS 2048
#define ND 1024
#define NH 16
#define HDIM 64
#define NM (NB * NS)              // 8192 rows total
#define MN_FULL ((size_t)NM * ND) // elements in full [B*S, D]
#define MN_B ((size_t)NS * ND)    // elements in per-batch [S, D]

// ---------------------------------------------------------------------------
// GEMM: C[M,1024] = A[M,1024] @ W[1024,1024]; M set by grid.x*128.
// f32 in, f32 out. Tile 128x128, BK=16, 256 threads, 8x8 micro-tile.
// ---------------------------------------------------------------------------
__global__ __launch_bounds__(256, 2)
void gemm_mk(const float* __restrict__ A, const float* __restrict__ W,
             float* __restrict__ C)
{
    constexpr int K = ND, N = ND;
    __shared__ float As[16][128];   // [k][m]
    __shared__ float Bs[16][128];   // [k][n]

    const int t  = threadIdx.x;
    const int bm = blockIdx.x * 128;
    const int bn = blockIdx.y * 128;

    const int r8 = (t >> 4) << 3;
    const int c4 = (t & 15) << 2;

    const int am = t >> 1;
    const int ak = (t & 1) << 3;
    const int bk  = t >> 4;
    const int bn0 = (t & 15) << 3;

    const float* Ap = A + (size_t)(bm + am) * K + ak;
    const float* Wp = W + (size_t)bk * N + bn + bn0;

    float acc[8][8];
#pragma unroll
    for (int i = 0; i < 8; ++i)
#pragma unroll
        for (int j = 0; j < 8; ++j) acc[i][j] = 0.f;

    for (int k0 = 0; k0 < K; k0 += 16) {
        float4 a0 = *(const float4*)(Ap + k0);
        float4 a1 = *(const float4*)(Ap + k0 + 4);
        float4 b0 = *(const float4*)(Wp + (size_t)k0 * N);
        float4 b1 = *(const float4*)(Wp + (size_t)k0 * N + 4);
        __syncthreads();
        As[ak + 0][am] = a0.x; As[ak + 1][am] = a0.y;
        As[ak + 2][am] = a0.z; As[ak + 3][am] = a0.w;
        As[ak + 4][am] = a1.x; As[ak + 5][am] = a1.y;
        As[ak + 6][am] = a1.z; As[ak + 7][am] = a1.w;
        *(float4*)&Bs[bk][bn0]     = b0;
        *(float4*)&Bs[bk][bn0 + 4] = b1;
        __syncthreads();
#pragma unroll
        for (int kk = 0; kk < 16; ++kk) {
            float4 av0 = *(const float4*)&As[kk][r8];
            float4 av1 = *(const float4*)&As[kk][r8 + 4];
            float4 bv0 = *(const float4*)&Bs[kk][c4];
            float4 bv1 = *(const float4*)&Bs[kk][c4 + 64];
            float ar[8] = {av0.x, av0.y, av0.z, av0.w, av1.x, av1.y, av1.z, av1.w};
            float br[8] = {bv0.x, bv0.y, bv0.z, bv0.w, bv1.x, bv1.y, bv1.z, bv1.w};
#pragma unroll
            for (int i = 0; i < 8; ++i)
#pragma unroll
                for (int j = 0; j < 8; ++j)
                    acc[i][j] = fmaf(ar[i], br[j], acc[i][j]);
        }
    }

#pragma unroll
    for (int i = 0; i < 8; ++i) {
        const size_t row = (size_t)(bm + r8 + i);
        float4 c0 = {acc[i][0], acc[i][1], acc[i][2], acc[i][3]};
        float4 c1 = {acc[i][4], acc[i][5], acc[i][6], acc[i][7]};
        *(float4*)(C + row * N + bn + c4)      = c0;
        *(float4*)(C + row * N + bn + 64 + c4) = c1;
    }
}

// ---------------------------------------------------------------------------
// Flash attention, f32, shuffle-free softmax (broadcast LDS reduction).
// grid = (S/64, H, nb), 256 threads. Q/K transposed in LDS; V row-major;
// Ps holds raw scores, then exp'd weights. Masked q-rows (q >= valid_len)
// get raw s=0 for all keys -> exactly uniform softmax (matches ref -1e5).
// ---------------------------------------------------------------------------
__global__ __launch_bounds__(256, 2)
void attn_f32(const float* __restrict__ Qg, const float* __restrict__ Kg,
              const float* __restrict__ Vg, const int* __restrict__ vlen_p,
              float* __restrict__ Og)
{
    __shared__ float QsT[64][64];
    __shared__ float KsT[64][64];
    __shared__ float Vs[64][64];
    __shared__ float Ps[64][64];

    const int t  = threadIdx.x;
    const int qt = blockIdx.x, h = blockIdx.y, b = blockIdx.z;
    const int tq = t >> 4;
    const int tk = t & 15;
    const int vlen = vlen_p[b];

    const size_t rowQ0  = (size_t)b * NS + (size_t)qt * 64;
    const size_t rowKV0 = (size_t)b * NS;
    const int col0 = h * HDIM;

    const int lr = t >> 2;
    const int lc = (t & 3) << 4;

    // ---- stage Q tile (transposed, pre-scaled by 1/sqrt(64)) ----
    {
        const float* src = Qg + (rowQ0 + lr) * ND + col0 + lc;
#pragma unroll
        for (int c = 0; c < 4; ++c) {
            float4 x = ((const float4*)src)[c];
            QsT[lc + c * 4 + 0][lr] = x.x * 0.125f;
            QsT[lc + c * 4 + 1][lr] = x.y * 0.125f;
            QsT[lc + c * 4 + 2][lr] = x.z * 0.125f;
            QsT[lc + c * 4 + 3][lr] = x.w * 0.125f;
        }
    }

    float m_i[4], l_i[4], oa[4][4];
    int mrow[4];
#pragma unroll
    for (int i = 0; i < 4; ++i) {
        m_i[i] = -1e30f; l_i[i] = 0.f;
        mrow[i] = (qt * 64 + tq * 4 + i) >= vlen;
#pragma unroll
        for (int j = 0; j < 4; ++j) oa[i][j] = 0.f;
    }

    for (int kt = 0; kt < NS / 64; ++kt) {
        __syncthreads();   // prior tile fully consumed (and Q staged, it 0)
        {
            const float* ksrc = Kg + (rowKV0 + kt * 64 + lr) * ND + col0 + lc;
            const float* vsrc = Vg + (rowKV0 + kt * 64 + lr) * ND + col0 + lc;
#pragma unroll
            for (int c = 0; c < 4; ++c) {
                float4 xk = ((const float4*)ksrc)[c];
                KsT[lc + c * 4 + 0][lr] = xk.x;
                KsT[lc + c * 4 + 1][lr] = xk.y;
                KsT[lc + c * 4 + 2][lr] = xk.z;
                KsT[lc + c * 4 + 3][lr] = xk.w;
                float4 xv = ((const float4*)vsrc)[c];
                *(float4*)&Vs[lr][lc + c * 4] = xv;
            }
        }
        __syncthreads();

        // ---- raw scores s[i][j] = (q/8) . k ----
        float s[4][4];
#pragma unroll
        for (int i = 0; i < 4; ++i)
#pragma unroll
            for (int j = 0; j < 4; ++j) s[i][j] = 0.f;

        for (int dd = 0; dd < 64; ++dd) {
            float4 q4 = *(const float4*)&QsT[dd][tq * 4];
            float4 k4 = *(const float4*)&KsT[dd][tk * 4];
            float qa[4] = {q4.x, q4.y, q4.z, q4.w};
            float ka[4] = {k4.x, k4.y, k4.z, k4.w};
#pragma unroll
            for (int i = 0; i < 4; ++i)
#pragma unroll
                for (int j = 0; j < 4; ++j)
                    s[i][j] = fmaf(qa[i], ka[j], s[i][j]);
        }

        // masked q-rows: raw score 0 for every key -> uniform weights
#pragma unroll
        for (int i = 0; i < 4; ++i)
            if (mrow[i]) {
#pragma unroll
                for (int j = 0; j < 4; ++j) s[i][j] = 0.f;
            }

        // ---- write raw scores ----
#pragma unroll
        for (int i = 0; i < 4; ++i) {
            float4 pw = {s[i][0], s[i][1], s[i][2], s[i][3]};
            *(float4*)&Ps[tq * 4 + i][tk * 4] = pw;
        }
        __syncthreads();   // raw Ps visible

        // ---- pass 1: full-row max via broadcast reads ----
        float mnew[4], corr[4];
#pragma unroll
        for (int i = 0; i < 4; ++i) {
            const int row = tq * 4 + i;
            float mx = -1e30f;
#pragma unroll
            for (int c = 0; c < 16; ++c) {
                float4 x = *(const float4*)&Ps[row][c * 4];
                mx = fmaxf(mx, fmaxf(fmaxf(x.x, x.y), fmaxf(x.z, x.w)));
            }
            mnew[i] = fmaxf(m_i[i], mx);
            corr[i] = __expf(m_i[i] - mnew[i]);
            m_i[i]  = mnew[i];
        }
        __syncthreads();   // all raw reads done

        // ---- exp own entries, write back ----
#pragma unroll
        for (int i = 0; i < 4; ++i) {
#pragma unroll
            for (int j = 0; j < 4; ++j) s[i][j] = __expf(s[i][j] - mnew[i]);
            float4 pw = {s[i][0], s[i][1], s[i][2], s[i][3]};
            *(float4*)&Ps[tq * 4 + i][tk * 4] = pw;
        }
        __syncthreads();   // exp'd Ps visible

        // ---- pass 2: full-row sum via broadcast reads; rescale O ----
#pragma unroll
        for (int i = 0; i < 4; ++i) {
            const int row = tq * 4 + i;
            float sum = 0.f;
#pragma unroll
            for (int c = 0; c < 16; ++c) {
                float4 x = *(const float4*)&Ps[row][c * 4];
                sum += (x.x + x.y) + (x.z + x.w);
            }
            l_i[i] = l_i[i] * corr[i] + sum;
#pragma unroll
            for (int j = 0; j < 4; ++j) oa[i][j] *= corr[i];
        }

        // ---- PV: oa[i][j] += sum_k P[row][k] * V[k][col] ----
        for (int kk = 0; kk < 64; kk += 4) {
            float4 p4[4], vv[4];
#pragma unroll
            for (int i = 0; i < 4; ++i) p4[i] = *(const float4*)&Ps[tq * 4 + i][kk];
#pragma unroll
            for (int c = 0; c < 4; ++c) vv[c] = *(const float4*)&Vs[kk + c][tk * 4];
#pragma unroll
            for (int i = 0; i < 4; ++i) {
                float pa[4] = {p4[i].x, p4[i].y, p4[i].z, p4[i].w};
#pragma unroll
                for (int c = 0; c < 4; ++c) {
                    oa[i][0] = fmaf(pa[c], vv[c].x, oa[i][0]);
                    oa[i][1] = fmaf(pa[c], vv[c].y, oa[i][1]);
                    oa[i][2] = fmaf(pa[c], vv[c].z, oa[i][2]);
                    oa[i][3] = fmaf(pa[c], vv[c].w, oa[i][3]);
                }
            }
        }
    }

    // ---- epilogue ----
#pragma unroll
    for (int i = 0; i < 4; ++i) {
        float r = 1.0f / l_i[i];
        float4 o4 = {oa[i][0] * r, oa[i][1] * r, oa[i][2] * r, oa[i][3] * r};
        *(float4*)(Og + (rowQ0 + tq * 4 + i) * ND + col0 + tk * 4) = o4;
    }
}

// ---------------------------------------------------------------------------
extern "C" void kernel_launch(void* const* d_in, const int* in_sizes, int n_in,
                              void* d_out, int out_size, void* d_ws, size_t ws_size,
                              hipStream_t stream)
{
    const float* queries = (const float*)d_in[0];
    const float* keys    = (const float*)d_in[1];
    const float* values  = (const float*)d_in[2];
    const int*   vlen    = (const int*)d_in[3];
    const float* Wq      = (const float*)d_in[4];
    const float* Wk      = (const float*)d_in[5];
    const float* Wv      = (const float*)d_in[6];
    const float* Wo      = (const float*)d_in[7];
    float* out           = (float*)d_out;   // reference output dtype is float32

    float* ws = (float*)d_ws;
    const size_t need_full = 4 * MN_FULL * sizeof(float);   // 128 MiB

    if (ws_size >= need_full) {
        // -------- full-batch path --------
        float* q  = ws;
        float* k  = ws + MN_FULL;
        float* v  = ws + 2 * MN_FULL;
        float* ao = ws + 3 * MN_FULL;

        dim3 gGrid(NM / 128, ND / 128);   // 64 x 8
        gemm_mk<<<gGrid, 256, 0, stream>>>(queries, Wq, q);
        gemm_mk<<<gGrid, 256, 0, stream>>>(keys,    Wk, k);
        gemm_mk<<<gGrid, 256, 0, stream>>>(values,  Wv, v);
        attn_f32<<<dim3(NS / 64, NH, NB), 256, 0, stream>>>(q, k, v, vlen, ao);
        gemm_mk<<<gGrid, 256, 0, stream>>>(ao, Wo, out);
    } else {
        // -------- per-batch path (needs 32 MiB of ws) --------
        float* q  = ws;
        float* k  = ws + MN_B;
        float* v  = ws + 2 * MN_B;
        float* ao = ws + 3 * MN_B;

        dim3 gGrid(NS / 128, ND / 128);   // 16 x 8
        for (int b = 0; b < NB; ++b) {
            const float* qin = queries + (size_t)b * MN_B;
            const float* kin = keys    + (size_t)b * MN_B;
            const float* vin = values  + (size_t)b * MN_B;
            float* ob = out + (size_t)b * MN_B;

            gemm_mk<<<gGrid, 256, 0, stream>>>(qin, Wq, q);
            gemm_mk<<<gGrid, 256, 0, stream>>>(kin, Wk, k);
            gemm_mk<<<gGrid, 256, 0, stream>>>(vin, Wv, v);
            attn_f32<<<dim3(NS / 64, NH, 1), 256, 0, stream>>>(q, k, v, vlen + b, ao);
            gemm_mk<<<gGrid, 256, 0, stream>>>(ao, Wo, ob);
        }
    }
}

// Round 4
// 1053.997 us; speedup vs baseline: 2.2975x; 2.2975x over previous
//
#include <hip/hip_runtime.h>
#include <hip/hip_bf16.h>

#define NB 4
#define NS 2048
#define ND 1024
#define NH 16
#define HDIM 64
#define NM (NB * NS)              // 8192 rows total
#define MN_FULL ((size_t)NM * ND) // elements per [B*S, D] matrix

typedef short short8 __attribute__((ext_vector_type(8)));
typedef short short4v __attribute__((ext_vector_type(4)));
typedef float f32x4 __attribute__((ext_vector_type(4)));

__device__ __forceinline__ short bf16rne(float f) {
    unsigned u = __builtin_bit_cast(unsigned, f);
    u += 0x7fff + ((u >> 16) & 1);
    return (short)(u >> 16);
}
__device__ __forceinline__ float bf2f(short s) {
    unsigned u = ((unsigned)(unsigned short)s) << 16;
    return __builtin_bit_cast(float, u);
}

// ---------------------------------------------------------------------------
// GEMM: C[8192,1024] = A @ W[1024,1024], f32 vector-FMA (proven kernel).
// EPI=0: f32 C.  EPI=1: hi/lo bf16 split (x*scale).  EPI=2: per-head V^T bf16.
// ---------------------------------------------------------------------------
template <int EPI>
__global__ __launch_bounds__(256, 2)
void gemm_epi(const float* __restrict__ A, const float* __restrict__ W,
              float* __restrict__ Cf, short* __restrict__ D1,
              short* __restrict__ D2, float scale)
{
    constexpr int K = ND, N = ND;
    __shared__ float As[16][128];
    __shared__ float Bs[16][128];

    const int t  = threadIdx.x;
    const int bm = blockIdx.x * 128;
    const int bn = blockIdx.y * 128;

    const int r8 = (t >> 4) << 3;
    const int c4 = (t & 15) << 2;

    const int am = t >> 1;
    const int ak = (t & 1) << 3;
    const int bk  = t >> 4;
    const int bn0 = (t & 15) << 3;

    const float* Ap = A + (size_t)(bm + am) * K + ak;
    const float* Wp = W + (size_t)bk * N + bn + bn0;

    float acc[8][8];
#pragma unroll
    for (int i = 0; i < 8; ++i)
#pragma unroll
        for (int j = 0; j < 8; ++j) acc[i][j] = 0.f;

    for (int k0 = 0; k0 < K; k0 += 16) {
        float4 a0 = *(const float4*)(Ap + k0);
        float4 a1 = *(const float4*)(Ap + k0 + 4);
        float4 b0 = *(const float4*)(Wp + (size_t)k0 * N);
        float4 b1 = *(const float4*)(Wp + (size_t)k0 * N + 4);
        __syncthreads();
        As[ak + 0][am] = a0.x; As[ak + 1][am] = a0.y;
        As[ak + 2][am] = a0.z; As[ak + 3][am] = a0.w;
        As[ak + 4][am] = a1.x; As[ak + 5][am] = a1.y;
        As[ak + 6][am] = a1.z; As[ak + 7][am] = a1.w;
        *(float4*)&Bs[bk][bn0]     = b0;
        *(float4*)&Bs[bk][bn0 + 4] = b1;
        __syncthreads();
#pragma unroll
        for (int kk = 0; kk < 16; ++kk) {
            float4 av0 = *(const float4*)&As[kk][r8];
            float4 av1 = *(const float4*)&As[kk][r8 + 4];
            float4 bv0 = *(const float4*)&Bs[kk][c4];
            float4 bv1 = *(const float4*)&Bs[kk][c4 + 64];
            float ar[8] = {av0.x, av0.y, av0.z, av0.w, av1.x, av1.y, av1.z, av1.w};
            float br[8] = {bv0.x, bv0.y, bv0.z, bv0.w, bv1.x, bv1.y, bv1.z, bv1.w};
#pragma unroll
            for (int i = 0; i < 8; ++i)
#pragma unroll
                for (int j = 0; j < 8; ++j)
                    acc[i][j] = fmaf(ar[i], br[j], acc[i][j]);
        }
    }

    if (EPI == 0) {
#pragma unroll
        for (int i = 0; i < 8; ++i) {
            const size_t row = (size_t)(bm + r8 + i);
            float4 c0 = {acc[i][0], acc[i][1], acc[i][2], acc[i][3]};
            float4 c1 = {acc[i][4], acc[i][5], acc[i][6], acc[i][7]};
            *(float4*)(Cf + row * N + bn + c4)      = c0;
            *(float4*)(Cf + row * N + bn + 64 + c4) = c1;
        }
    } else if (EPI == 1) {
#pragma unroll
        for (int i = 0; i < 8; ++i) {
            const size_t row = (size_t)(bm + r8 + i);
#pragma unroll
            for (int half = 0; half < 2; ++half) {
                short4v hv, lv;
#pragma unroll
                for (int j = 0; j < 4; ++j) {
                    float x = acc[i][half * 4 + j] * scale;
                    short hi = bf16rne(x);
                    hv[j] = hi;
                    lv[j] = bf16rne(x - bf2f(hi));
                }
                const size_t off = row * N + bn + 64 * half + c4;
                *(short4v*)(D1 + off) = hv;
                *(short4v*)(D2 + off) = lv;
            }
        }
    } else {  // EPI == 2 : VT[b][h][d][s] bf16
        const int b_  = (bm + r8) >> 11;
        const int s0_ = (bm & (NS - 1)) + r8;
#pragma unroll
        for (int half = 0; half < 2; ++half)
#pragma unroll
            for (int j = 0; j < 4; ++j) {
                const int col = bn + 64 * half + c4 + j;
                const int h_ = col >> 6, d_ = col & 63;
                short8 vv;
#pragma unroll
                for (int i = 0; i < 8; ++i) vv[i] = bf16rne(acc[i][half * 4 + j]);
                *(short8*)(D1 + ((size_t)((b_ * NH + h_) * HDIM + d_)) * NS + s0_) = vv;
            }
    }
}

// ---------------------------------------------------------------------------
// MFMA flash attention. grid=(S/64, H, B), 256 thr (4 waves x 16 q-rows).
// QK^T: bf16 hi/lo split-3 (f32-accurate scores). PV: plain bf16.
// All LDS tiles [64][64] bf16, XOR-swizzled: elem col ^= (row&7)<<3.
// ---------------------------------------------------------------------------
__global__ __launch_bounds__(256, 2)
void attn_mfma(const short* __restrict__ Qhi, const short* __restrict__ Qlo,
               const short* __restrict__ Khi_g, const short* __restrict__ Klo_g,
               const short* __restrict__ VTg, const int* __restrict__ vlen_p,
               float* __restrict__ Og)
{
    __shared__ char smem[32768];
    short* Khs = (short*)smem;              // 8KB
    short* Kls = (short*)(smem + 8192);     // 8KB
    short* Vts = (short*)(smem + 16384);    // 8KB
    short* Pss = (short*)(smem + 24576);    // 8KB

    const int t = threadIdx.x;
    const int w = t >> 6, l = t & 63, g = l >> 4, li = l & 15;
    const int qt = blockIdx.x, h = blockIdx.y, b = blockIdx.z;
    const int vlen = vlen_p[b];
    const int q0 = qt * 64;

    // ---- hoisted Q A-frags (lane: q-row = w*16+li, d = ks*32 + g*8 + j) ----
    short8 qh[2], ql[2];
    {
        const size_t base = ((size_t)(b * NS) + q0 + w * 16 + li) * ND + h * HDIM;
#pragma unroll
        for (int ks = 0; ks < 2; ++ks) {
            qh[ks] = *(const short8*)(Qhi + base + ks * 32 + g * 8);
            ql[ks] = *(const short8*)(Qlo + base + ks * 32 + g * 8);
        }
    }

    const int sr = t >> 2, sc = (t & 3) << 4;          // staging row/col
    const size_t kbase = ((size_t)(b * NS) + sr) * ND + h * HDIM + sc;
    const size_t vbase = ((size_t)((b * NH + h) * HDIM) + sr) * NS + sc;
    const int wsw = (sr & 7) << 3;

    float m_[4], l_[4];
    f32x4 o_[4];
#pragma unroll
    for (int r = 0; r < 4; ++r) { m_[r] = -1e30f; l_[r] = 0.f; }
#pragma unroll
    for (int dt = 0; dt < 4; ++dt) o_[dt] = (f32x4){0.f, 0.f, 0.f, 0.f};

    int mrow[4];
#pragma unroll
    for (int r = 0; r < 4; ++r) mrow[r] = (q0 + w * 16 + 4 * g + r) >= vlen;

    for (int kt = 0; kt < NS / 64; ++kt) {
        __syncthreads();   // prior tile fully consumed
        {
            const short* kp = Khi_g + kbase + (size_t)kt * 64 * ND;
            const short* lp = Klo_g + kbase + (size_t)kt * 64 * ND;
            const short* vp = VTg + vbase + kt * 64;
            short8 a0 = *(const short8*)kp, a1 = *(const short8*)(kp + 8);
            short8 b0 = *(const short8*)lp, b1 = *(const short8*)(lp + 8);
            short8 c0 = *(const short8*)vp, c1 = *(const short8*)(vp + 8);
            const int wb = sr * 64;
            *(short8*)&Khs[wb + (sc ^ wsw)]       = a0;
            *(short8*)&Khs[wb + ((sc + 8) ^ wsw)] = a1;
            *(short8*)&Kls[wb + (sc ^ wsw)]       = b0;
            *(short8*)&Kls[wb + ((sc + 8) ^ wsw)] = b1;
            *(short8*)&Vts[wb + (sc ^ wsw)]       = c0;
            *(short8*)&Vts[wb + ((sc + 8) ^ wsw)] = c1;
        }
        __syncthreads();

        // ---- QK^T: S[q=w16+4g+r][k=li+16*t4], split-3 ----
        f32x4 s[4];
#pragma unroll
        for (int t4 = 0; t4 < 4; ++t4) {
            f32x4 acc = (f32x4){0.f, 0.f, 0.f, 0.f};
            const int row = li + 16 * t4;
            const int rb = row * 64, rs = (row & 7) << 3;
#pragma unroll
            for (int ks = 0; ks < 2; ++ks) {
                const int cc = (ks * 32 + g * 8) ^ rs;
                short8 bh = *(const short8*)&Khs[rb + cc];
                short8 bl = *(const short8*)&Kls[rb + cc];
                acc = __builtin_amdgcn_mfma_f32_16x16x32_bf16(ql[ks], bh, acc, 0, 0, 0);
                acc = __builtin_amdgcn_mfma_f32_16x16x32_bf16(qh[ks], bl, acc, 0, 0, 0);
                acc = __builtin_amdgcn_mfma_f32_16x16x32_bf16(qh[ks], bh, acc, 0, 0, 0);
            }
            s[t4] = acc;
        }

        // ---- online softmax (row r lives in 16 lanes sharing (w,g)) ----
        const int prow_ = w * 16 + 4 * g;
#pragma unroll
        for (int r = 0; r < 4; ++r) {
            float s0 = mrow[r] ? 0.f : s[0][r];
            float s1 = mrow[r] ? 0.f : s[1][r];
            float s2 = mrow[r] ? 0.f : s[2][r];
            float s3 = mrow[r] ? 0.f : s[3][r];
            float mx = fmaxf(fmaxf(s0, s1), fmaxf(s2, s3));
            mx = fmaxf(mx, __shfl_xor(mx, 1));
            mx = fmaxf(mx, __shfl_xor(mx, 2));
            mx = fmaxf(mx, __shfl_xor(mx, 4));
            mx = fmaxf(mx, __shfl_xor(mx, 8));
            float mn = fmaxf(m_[r], mx);
            float corr = __expf(m_[r] - mn);
            m_[r] = mn;
            float p0 = __expf(s0 - mn), p1 = __expf(s1 - mn);
            float p2 = __expf(s2 - mn), p3 = __expf(s3 - mn);
            float sum = (p0 + p1) + (p2 + p3);
            sum += __shfl_xor(sum, 1);
            sum += __shfl_xor(sum, 2);
            sum += __shfl_xor(sum, 4);
            sum += __shfl_xor(sum, 8);
            l_[r] = l_[r] * corr + sum;
#pragma unroll
            for (int dt = 0; dt < 4; ++dt) o_[dt][r] *= corr;
            const int pr = prow_ + r;
            const int prb = pr * 64, prs = (pr & 7) << 3;
            Pss[prb + ((li + 0)  ^ prs)] = bf16rne(p0);
            Pss[prb + ((li + 16) ^ prs)] = bf16rne(p1);
            Pss[prb + ((li + 32) ^ prs)] = bf16rne(p2);
            Pss[prb + ((li + 48) ^ prs)] = bf16rne(p3);
        }

        // ---- PV: O[q][d] += P[q][k] * VT[d][k]  (same-wave LDS RAW only) ----
        {
            const int ar = w * 16 + li;
            const int arb = ar * 64, ars = (ar & 7) << 3;
            short8 pa0 = *(const short8*)&Pss[arb + ((g * 8) ^ ars)];
            short8 pa1 = *(const short8*)&Pss[arb + ((32 + g * 8) ^ ars)];
#pragma unroll
            for (int dt = 0; dt < 4; ++dt) {
                const int vr = li + 16 * dt;
                const int vrb = vr * 64, vrs = (vr & 7) << 3;
                short8 vb0 = *(const short8*)&Vts[vrb + ((g * 8) ^ vrs)];
                short8 vb1 = *(const short8*)&Vts[vrb + ((32 + g * 8) ^ vrs)];
                o_[dt] = __builtin_amdgcn_mfma_f32_16x16x32_bf16(pa0, vb0, o_[dt], 0, 0, 0);
                o_[dt] = __builtin_amdgcn_mfma_f32_16x16x32_bf16(pa1, vb1, o_[dt], 0, 0, 0);
            }
        }
    }

    // ---- epilogue: normalize, transpose via LDS, coalesced store ----
    __syncthreads();
    float* Ol = (float*)smem;   // [64][68] f32 = 17408B (fits in 32KB)
    float rin[4];
#pragma unroll
    for (int r = 0; r < 4; ++r) rin[r] = 1.0f / l_[r];
#pragma unroll
    for (int dt = 0; dt < 4; ++dt)
#pragma unroll
        for (int r = 0; r < 4; ++r)
            Ol[(w * 16 + 4 * g + r) * 68 + li + 16 * dt] = o_[dt][r] * rin[r];
    __syncthreads();
    {
        const size_t orow = (size_t)b * NS + q0 + sr;
        float* dst = Og + orow * ND + h * HDIM + sc;
        const float* src = &Ol[sr * 68 + sc];
#pragma unroll
        for (int j = 0; j < 4; ++j)
            *(float4*)(dst + j * 4) = *(const float4*)(src + j * 4);
    }
}

// ---------------------------------------------------------------------------
extern "C" void kernel_launch(void* const* d_in, const int* in_sizes, int n_in,
                              void* d_out, int out_size, void* d_ws, size_t ws_size,
                              hipStream_t stream)
{
    const float* queries = (const float*)d_in[0];
    const float* keys    = (const float*)d_in[1];
    const float* values  = (const float*)d_in[2];
    const int*   vlen    = (const int*)d_in[3];
    const float* Wq      = (const float*)d_in[4];
    const float* Wk      = (const float*)d_in[5];
    const float* Wv      = (const float*)d_in[6];
    const float* Wo      = (const float*)d_in[7];
    float* out           = (float*)d_out;

    // ws layout (117.4 MB; ws >= 128 MiB confirmed by round-3 full path):
    short* Qhi = (short*)d_ws;
    short* Qlo = Qhi + MN_FULL;
    short* Khi = Qlo + MN_FULL;
    short* Klo = Khi + MN_FULL;
    short* VT  = Klo + MN_FULL;
    float* ao  = (float*)(VT + MN_FULL);

    dim3 gGrid(NM / 128, ND / 128);   // 64 x 8
    gemm_epi<1><<<gGrid, 256, 0, stream>>>(queries, Wq, nullptr, Qhi, Qlo, 0.125f);
    gemm_epi<1><<<gGrid, 256, 0, stream>>>(keys,    Wk, nullptr, Khi, Klo, 1.0f);
    gemm_epi<2><<<gGrid, 256, 0, stream>>>(values,  Wv, nullptr, VT,  nullptr, 1.0f);

    attn_mfma<<<dim3(NS / 64, NH, NB), 256, 0, stream>>>(Qhi, Qlo, Khi, Klo, VT, vlen, ao);

    gemm_epi<0><<<gGrid, 256, 0, stream>>>(ao, Wo, out, nullptr, nullptr, 1.0f);
}

// Round 5
// 480.256 us; speedup vs baseline: 5.0422x; 2.1947x over previous
//
#include <hip/hip_runtime.h>
#include <hip/hip_bf16.h>

#define NB 4
#define NS 2048
#define ND 1024
#define NH 16
#define HDIM 64
#define NM (NB * NS)
#define MN_FULL ((size_t)NM * ND)

typedef short short8 __attribute__((ext_vector_type(8)));
typedef short short4v __attribute__((ext_vector_type(4)));
typedef float f32x4 __attribute__((ext_vector_type(4)));

__device__ __forceinline__ short bf16rne(float f) {
    unsigned u = __builtin_bit_cast(unsigned, f);
    u += 0x7fff + ((u >> 16) & 1);
    return (short)(u >> 16);
}
__device__ __forceinline__ float bf2f(short s) {
    unsigned u = ((unsigned)(unsigned short)s) << 16;
    return __builtin_bit_cast(float, u);
}
__device__ __forceinline__ void gl_lds16(const short* g, short* l) {
    __builtin_amdgcn_global_load_lds(
        (const __attribute__((address_space(1))) void*)g,
        (__attribute__((address_space(3))) void*)l, 16, 0, 0);
}

// ---------------------------------------------------------------------------
// convA: f32 [M,1024] -> hi/lo bf16, swizzled within k-64 chunks by (m&7).
// ---------------------------------------------------------------------------
__global__ __launch_bounds__(256)
void convA(const float* __restrict__ A, short* __restrict__ Ah, short* __restrict__ Al)
{
    const size_t idx = (size_t)blockIdx.x * 256 + threadIdx.x;   // one 8-elem chunk
    const int m = (int)(idx >> 7);
    const int k = (int)((idx & 127) << 3);
    const float* src = A + ((size_t)m << 10) + k;
    float4 x0 = *(const float4*)src;
    float4 x1 = *(const float4*)(src + 4);
    float xv[8] = {x0.x, x0.y, x0.z, x0.w, x1.x, x1.y, x1.z, x1.w};
    short8 hv, lv;
#pragma unroll
    for (int j = 0; j < 8; ++j) {
        short h = bf16rne(xv[j]);
        hv[j] = h;
        lv[j] = bf16rne(xv[j] - bf2f(h));
    }
    const int ksw = (k & ~63) | ((k & 63) ^ ((m & 7) << 3));
    *(short8*)(Ah + ((size_t)m << 10) + ksw) = hv;
    *(short8*)(Al + ((size_t)m << 10) + ksw) = lv;
}

// ---------------------------------------------------------------------------
// convW: f32 W[k][n] -> W^T hi/lo bf16 [n][k], swizzled by (n&7).
// ---------------------------------------------------------------------------
__global__ __launch_bounds__(256)
void convW(const float* __restrict__ W, short* __restrict__ Wh, short* __restrict__ Wl)
{
    const int idx = blockIdx.x * 256 + threadIdx.x;
    const int n = idx & 1023;
    const int k = (idx >> 10) << 3;
    short8 hv, lv;
#pragma unroll
    for (int j = 0; j < 8; ++j) {
        float x = W[(size_t)(k + j) * ND + n];
        short h = bf16rne(x);
        hv[j] = h;
        lv[j] = bf16rne(x - bf2f(h));
    }
    const int ksw = (k & ~63) | ((k & 63) ^ ((n & 7) << 3));
    *(short8*)(Wh + ((size_t)n << 10) + ksw) = hv;
    *(short8*)(Wl + ((size_t)n << 10) + ksw) = lv;
}

// ---------------------------------------------------------------------------
// MFMA GEMM, split-3 bf16: C = A*B^T(kind of): D[row][col] = sum_k A[row][k]*B[col][k].
// A: [rowsA, 1024] hi/lo swizzled; B: [rowsB, 1024] hi/lo swizzled.
// grid = (rowsA/128, rowsB/128), 256 threads, 64KB LDS, global_load_lds staging.
// EPI 0: f32 C[row][col]. EPI 1: hi/lo bf16 (scale). EPI 2: VT (row=n->h,d; col=m->b,s).
// ---------------------------------------------------------------------------
template <int EPI>
__global__ __launch_bounds__(256, 2)
void gemm_mfma(const short* __restrict__ Ah, const short* __restrict__ Al,
               const short* __restrict__ Bh, const short* __restrict__ Bl,
               float* __restrict__ Cf, short* __restrict__ D1,
               short* __restrict__ D2, float scale)
{
    __shared__ short lds[32768];           // 64 KB
    short* AhS = lds;
    short* AlS = lds + 8192;
    short* BhS = lds + 16384;
    short* BlS = lds + 24576;

    const int t = threadIdx.x, w = t >> 6, l = t & 63;
    const int g = l >> 4, li = l & 15;
    const int wr = w >> 1, wc = w & 1;
    const size_t bm = (size_t)blockIdx.x * 128, bn = (size_t)blockIdx.y * 128;

    f32x4 acc[4][4];
#pragma unroll
    for (int i = 0; i < 4; ++i)
#pragma unroll
        for (int j = 0; j < 4; ++j) acc[i][j] = (f32x4){0.f, 0.f, 0.f, 0.f};

    // staging: wave w covers rows [w*32, w*32+32) of each [128][64] tile
    const int srow = w * 32 + (l >> 3);
    const int schk = (l & 7) << 3;
    const short* pAh = Ah + (bm + srow) * 1024 + schk;
    const short* pAl = Al + (bm + srow) * 1024 + schk;
    const short* pBh = Bh + (bn + srow) * 1024 + schk;
    const short* pBl = Bl + (bn + srow) * 1024 + schk;
    const int lbase = w * 32 * 64;

    for (int kt = 0; kt < 16; ++kt) {
        const int k0 = kt * 64;
        __syncthreads();
#pragma unroll
        for (int r = 0; r < 4; ++r) {
            const int go = r * 8 * 1024 + k0;
            const int lo_ = lbase + r * 512;
            gl_lds16(pAh + go, AhS + lo_);
            gl_lds16(pAl + go, AlS + lo_);
            gl_lds16(pBh + go, BhS + lo_);
            gl_lds16(pBl + go, BlS + lo_);
        }
        __syncthreads();
#pragma unroll
        for (int ks = 0; ks < 2; ++ks) {
            short8 fah[4], fal[4], fbh[4], fbl[4];
#pragma unroll
            for (int i = 0; i < 4; ++i) {
                const int m = wr * 64 + i * 16 + li;
                const int c = (ks * 32 + g * 8) ^ ((m & 7) << 3);
                fah[i] = *(const short8*)&AhS[m * 64 + c];
                fal[i] = *(const short8*)&AlS[m * 64 + c];
                const int n = wc * 64 + i * 16 + li;
                const int cn = (ks * 32 + g * 8) ^ ((n & 7) << 3);
                fbh[i] = *(const short8*)&BhS[n * 64 + cn];
                fbl[i] = *(const short8*)&BlS[n * 64 + cn];
            }
#pragma unroll
            for (int i = 0; i < 4; ++i)
#pragma unroll
                for (int j = 0; j < 4; ++j) {
                    acc[i][j] = __builtin_amdgcn_mfma_f32_16x16x32_bf16(fal[i], fbh[j], acc[i][j], 0, 0, 0);
                    acc[i][j] = __builtin_amdgcn_mfma_f32_16x16x32_bf16(fah[i], fbl[j], acc[i][j], 0, 0, 0);
                    acc[i][j] = __builtin_amdgcn_mfma_f32_16x16x32_bf16(fah[i], fbh[j], acc[i][j], 0, 0, 0);
                }
        }
    }

    // ---- epilogue: LDS bounce (wave-private 16KB region), coalesced store ----
    __syncthreads();
    float* Ofs = (float*)lds + w * 4096;   // [64][64] f32
#pragma unroll
    for (int i = 0; i < 4; ++i)
#pragma unroll
        for (int j = 0; j < 4; ++j)
#pragma unroll
            for (int r = 0; r < 4; ++r)
                Ofs[(i * 16 + g * 4 + r) * 64 + j * 16 + li] = acc[i][j][r];
    __syncthreads();

    if (EPI == 0 || EPI == 1) {
        const int irow = l >> 2, chunk = l & 3;
#pragma unroll
        for (int rb = 0; rb < 4; ++rb)
#pragma unroll
            for (int cb = 0; cb < 4; ++cb) {
                float4 x = *(const float4*)&Ofs[(rb * 16 + irow) * 64 + cb * 16 + chunk * 4];
                const size_t rg = bm + wr * 64 + rb * 16 + irow;
                const size_t cg = bn + wc * 64 + cb * 16 + chunk * 4;
                if (EPI == 0) {
                    *(float4*)(Cf + rg * 1024 + cg) = x;
                } else {
                    float xs[4] = {x.x * scale, x.y * scale, x.z * scale, x.w * scale};
                    short4v hv, lv;
#pragma unroll
                    for (int jj = 0; jj < 4; ++jj) {
                        short h = bf16rne(xs[jj]);
                        hv[jj] = h;
                        lv[jj] = bf16rne(xs[jj] - bf2f(h));
                    }
                    *(short4v*)(D1 + rg * 1024 + cg) = hv;
                    *(short4v*)(D2 + rg * 1024 + cg) = lv;
                }
            }
    } else {   // EPI == 2: rows = n of W^T -> (h,d); cols = m -> (b,s); VT[b][h][d][s]
        const int nr = l >> 3, mc = l & 7;
#pragma unroll
        for (int p = 0; p < 8; ++p) {
            const int nl = p * 8 + nr;
            float4 x0 = *(const float4*)&Ofs[nl * 64 + mc * 8];
            float4 x1 = *(const float4*)&Ofs[nl * 64 + mc * 8 + 4];
            short8 v;
            v[0] = bf16rne(x0.x); v[1] = bf16rne(x0.y);
            v[2] = bf16rne(x0.z); v[3] = bf16rne(x0.w);
            v[4] = bf16rne(x1.x); v[5] = bf16rne(x1.y);
            v[6] = bf16rne(x1.z); v[7] = bf16rne(x1.w);
            const int ng = (int)bm + wr * 64 + nl;
            const size_t mg = bn + wc * 64 + mc * 8;
            const int h_ = ng >> 6, d_ = ng & 63;
            const int b_ = (int)(mg >> 11), s_ = (int)(mg & 2047);
            *(short8*)(D1 + (((size_t)(b_ * NH + h_) * HDIM + d_) << 11) + s_) = v;
        }
    }
}

// ---------------------------------------------------------------------------
// MFMA flash attention (round-4 proven). Epilogue now emits hi/lo bf16,
// pre-swizzled as A-input for the Wo GEMM.
// ---------------------------------------------------------------------------
__global__ __launch_bounds__(256, 2)
void attn_mfma(const short* __restrict__ Qhi, const short* __restrict__ Qlo,
               const short* __restrict__ Khi_g, const short* __restrict__ Klo_g,
               const short* __restrict__ VTg, const int* __restrict__ vlen_p,
               short* __restrict__ AOh, short* __restrict__ AOl)
{
    __shared__ char smem[32768];
    short* Khs = (short*)smem;
    short* Kls = (short*)(smem + 8192);
    short* Vts = (short*)(smem + 16384);
    short* Pss = (short*)(smem + 24576);

    const int t = threadIdx.x;
    const int w = t >> 6, l = t & 63, g = l >> 4, li = l & 15;
    const int qt = blockIdx.x, h = blockIdx.y, b = blockIdx.z;
    const int vlen = vlen_p[b];
    const int q0 = qt * 64;

    short8 qh[2], ql[2];
    {
        const size_t base = ((size_t)(b * NS) + q0 + w * 16 + li) * ND + h * HDIM;
#pragma unroll
        for (int ks = 0; ks < 2; ++ks) {
            qh[ks] = *(const short8*)(Qhi + base + ks * 32 + g * 8);
            ql[ks] = *(const short8*)(Qlo + base + ks * 32 + g * 8);
        }
    }

    const int sr = t >> 2, sc = (t & 3) << 4;
    const size_t kbase = ((size_t)(b * NS) + sr) * ND + h * HDIM + sc;
    const size_t vbase = ((size_t)((b * NH + h) * HDIM) + sr) * NS + sc;
    const int wsw = (sr & 7) << 3;

    float m_[4], l_[4];
    f32x4 o_[4];
#pragma unroll
    for (int r = 0; r < 4; ++r) { m_[r] = -1e30f; l_[r] = 0.f; }
#pragma unroll
    for (int dt = 0; dt < 4; ++dt) o_[dt] = (f32x4){0.f, 0.f, 0.f, 0.f};

    int mrow[4];
#pragma unroll
    for (int r = 0; r < 4; ++r) mrow[r] = (q0 + w * 16 + 4 * g + r) >= vlen;

    for (int kt = 0; kt < NS / 64; ++kt) {
        __syncthreads();
        {
            const short* kp = Khi_g + kbase + (size_t)kt * 64 * ND;
            const short* lp = Klo_g + kbase + (size_t)kt * 64 * ND;
            const short* vp = VTg + vbase + kt * 64;
            short8 a0 = *(const short8*)kp, a1 = *(const short8*)(kp + 8);
            short8 b0 = *(const short8*)lp, b1 = *(const short8*)(lp + 8);
            short8 c0 = *(const short8*)vp, c1 = *(const short8*)(vp + 8);
            const int wb = sr * 64;
            *(short8*)&Khs[wb + (sc ^ wsw)]       = a0;
            *(short8*)&Khs[wb + ((sc + 8) ^ wsw)] = a1;
            *(short8*)&Kls[wb + (sc ^ wsw)]       = b0;
            *(short8*)&Kls[wb + ((sc + 8) ^ wsw)] = b1;
            *(short8*)&Vts[wb + (sc ^ wsw)]       = c0;
            *(short8*)&Vts[wb + ((sc + 8) ^ wsw)] = c1;
        }
        __syncthreads();

        f32x4 s[4];
#pragma unroll
        for (int t4 = 0; t4 < 4; ++t4) {
            f32x4 acc = (f32x4){0.f, 0.f, 0.f, 0.f};
            const int row = li + 16 * t4;
            const int rb = row * 64, rs = (row & 7) << 3;
#pragma unroll
            for (int ks = 0; ks < 2; ++ks) {
                const int cc = (ks * 32 + g * 8) ^ rs;
                short8 bh = *(const short8*)&Khs[rb + cc];
                short8 bl = *(const short8*)&Kls[rb + cc];
                acc = __builtin_amdgcn_mfma_f32_16x16x32_bf16(ql[ks], bh, acc, 0, 0, 0);
                acc = __builtin_amdgcn_mfma_f32_16x16x32_bf16(qh[ks], bl, acc, 0, 0, 0);
                acc = __builtin_amdgcn_mfma_f32_16x16x32_bf16(qh[ks], bh, acc, 0, 0, 0);
            }
            s[t4] = acc;
        }

        const int prow_ = w * 16 + 4 * g;
#pragma unroll
        for (int r = 0; r < 4; ++r) {
            float s0 = mrow[r] ? 0.f : s[0][r];
            float s1 = mrow[r] ? 0.f : s[1][r];
            float s2 = mrow[r] ? 0.f : s[2][r];
            float s3 = mrow[r] ? 0.f : s[3][r];
            float mx = fmaxf(fmaxf(s0, s1), fmaxf(s2, s3));
            mx = fmaxf(mx, __shfl_xor(mx, 1));
            mx = fmaxf(mx, __shfl_xor(mx, 2));
            mx = fmaxf(mx, __shfl_xor(mx, 4));
            mx = fmaxf(mx, __shfl_xor(mx, 8));
            float mn = fmaxf(m_[r], mx);
            float corr = __expf(m_[r] - mn);
            m_[r] = mn;
            float p0 = __expf(s0 - mn), p1 = __expf(s1 - mn);
            float p2 = __expf(s2 - mn), p3 = __expf(s3 - mn);
            float sum = (p0 + p1) + (p2 + p3);
            sum += __shfl_xor(sum, 1);
            sum += __shfl_xor(sum, 2);
            sum += __shfl_xor(sum, 4);
            sum += __shfl_xor(sum, 8);
            l_[r] = l_[r] * corr + sum;
#pragma unroll
            for (int dt = 0; dt < 4; ++dt) o_[dt][r] *= corr;
            const int pr = prow_ + r;
            const int prb = pr * 64, prs = (pr & 7) << 3;
            Pss[prb + ((li + 0)  ^ prs)] = bf16rne(p0);
            Pss[prb + ((li + 16) ^ prs)] = bf16rne(p1);
            Pss[prb + ((li + 32) ^ prs)] = bf16rne(p2);
            Pss[prb + ((li + 48) ^ prs)] = bf16rne(p3);
        }

        {
            const int ar = w * 16 + li;
            const int arb = ar * 64, ars = (ar & 7) << 3;
            short8 pa0 = *(const short8*)&Pss[arb + ((g * 8) ^ ars)];
            short8 pa1 = *(const short8*)&Pss[arb + ((32 + g * 8) ^ ars)];
#pragma unroll
            for (int dt = 0; dt < 4; ++dt) {
                const int vr = li + 16 * dt;
                const int vrb = vr * 64, vrs = (vr & 7) << 3;
                short8 vb0 = *(const short8*)&Vts[vrb + ((g * 8) ^ vrs)];
                short8 vb1 = *(const short8*)&Vts[vrb + ((32 + g * 8) ^ vrs)];
                o_[dt] = __builtin_amdgcn_mfma_f32_16x16x32_bf16(pa0, vb0, o_[dt], 0, 0, 0);
                o_[dt] = __builtin_amdgcn_mfma_f32_16x16x32_bf16(pa1, vb1, o_[dt], 0, 0, 0);
            }
        }
    }

    // ---- epilogue: normalize, LDS transpose, emit hi/lo swizzled bf16 ----
    __syncthreads();
    float* Ol = (float*)smem;   // [64][68] f32
    float rin[4];
#pragma unroll
    for (int r = 0; r < 4; ++r) rin[r] = 1.0f / l_[r];
#pragma unroll
    for (int dt = 0; dt < 4; ++dt)
#pragma unroll
        for (int r = 0; r < 4; ++r)
            Ol[(w * 16 + 4 * g + r) * 68 + li + 16 * dt] = o_[dt][r] * rin[r];
    __syncthreads();
    {
        const size_t morow = (size_t)b * NS + q0 + sr;   // global A-row for Wo GEMM
        const float* src = &Ol[sr * 68 + sc];
        const int swz = (sr & 7) << 3;
#pragma unroll
        for (int c = 0; c < 2; ++c) {
            float4 x0 = *(const float4*)(src + c * 8);
            float4 x1 = *(const float4*)(src + c * 8 + 4);
            float xv[8] = {x0.x, x0.y, x0.z, x0.w, x1.x, x1.y, x1.z, x1.w};
            short8 hv, lv;
#pragma unroll
            for (int j = 0; j < 8; ++j) {
                short hh = bf16rne(xv[j]);
                hv[j] = hh;
                lv[j] = bf16rne(xv[j] - bf2f(hh));
            }
            const size_t dst = morow * ND + h * HDIM + ((sc + c * 8) ^ swz);
            *(short8*)(AOh + dst) = hv;
            *(short8*)(AOl + dst) = lv;
        }
    }
}

// ---------------------------------------------------------------------------
extern "C" void kernel_launch(void* const* d_in, const int* in_sizes, int n_in,
                              void* d_out, int out_size, void* d_ws, size_t ws_size,
                              hipStream_t stream)
{
    const float* queries = (const float*)d_in[0];
    const float* keys    = (const float*)d_in[1];
    const float* values  = (const float*)d_in[2];
    const int*   vlen    = (const int*)d_in[3];
    const float* Wq      = (const float*)d_in[4];
    const float* Wk      = (const float*)d_in[5];
    const float* Wv      = (const float*)d_in[6];
    const float* Wo      = (const float*)d_in[7];
    float* out           = (float*)d_out;

    // ws: Ab(h/l) 2x8M | Wb(h/l) 2x1M | Qhi Qlo Khi Klo 4x8M | VT 8M  = 116 MB
    short* Abh = (short*)d_ws;
    short* Abl = Abh + MN_FULL;
    short* Wbh = Abl + MN_FULL;
    short* Wbl = Wbh + (size_t)ND * ND;
    short* Qhi = Wbl + (size_t)ND * ND;
    short* Qlo = Qhi + MN_FULL;
    short* Khi = Qlo + MN_FULL;
    short* Klo = Khi + MN_FULL;
    short* VT  = Klo + MN_FULL;
    short* AOh = Abh;   // reuse after projections
    short* AOl = Abl;

    const int gA = (int)(MN_FULL / 8 / 256);        // 4096
    const int gW = (int)((size_t)ND * ND / 8 / 256); // 512
    dim3 gP(NM / 128, ND / 128);                    // (64, 8)
    dim3 gV(ND / 128, NM / 128);                    // (8, 64)

    // Q projection
    convA<<<gA, 256, 0, stream>>>(queries, Abh, Abl);
    convW<<<gW, 256, 0, stream>>>(Wq, Wbh, Wbl);
    gemm_mfma<1><<<gP, 256, 0, stream>>>(Abh, Abl, Wbh, Wbl, nullptr, Qhi, Qlo, 0.125f);
    // K projection
    convA<<<gA, 256, 0, stream>>>(keys, Abh, Abl);
    convW<<<gW, 256, 0, stream>>>(Wk, Wbh, Wbl);
    gemm_mfma<1><<<gP, 256, 0, stream>>>(Abh, Abl, Wbh, Wbl, nullptr, Khi, Klo, 1.0f);
    // V projection (transposed output: operands swapped)
    convA<<<gA, 256, 0, stream>>>(values, Abh, Abl);
    convW<<<gW, 256, 0, stream>>>(Wv, Wbh, Wbl);
    gemm_mfma<2><<<gV, 256, 0, stream>>>(Wbh, Wbl, Abh, Abl, nullptr, VT, nullptr, 1.0f);
    // attention -> hi/lo swizzled ao (into Ab region)
    attn_mfma<<<dim3(NS / 64, NH, NB), 256, 0, stream>>>(Qhi, Qlo, Khi, Klo, VT, vlen, AOh, AOl);
    // output projection
    convW<<<gW, 256, 0, stream>>>(Wo, Wbh, Wbl);
    gemm_mfma<0><<<gP, 256, 0, stream>>>(AOh, AOl, Wbh, Wbl, out, nullptr, nullptr, 1.0f);
}